// Round 1
// 614.130 us; speedup vs baseline: 1.0130x; 1.0130x over previous
//
#include <hip/hip_runtime.h>
#include <math.h>

#define D 1024
#define NROW 128
#define PANEL 16
#define NPANELS 8
#define NTHREADS 1024
#define XP 1028   // Xc row pitch in floats: +16B rotates banks per row
#define QP 1032   // Qb row pitch in bf16:  +16B ditto

typedef __attribute__((ext_vector_type(8))) short short8;
typedef __attribute__((ext_vector_type(4))) float floatx4;

__device__ __forceinline__ unsigned short f2bf(float f) {  // RNE f32 -> bf16 (inputs finite)
  unsigned int u = __builtin_bit_cast(unsigned int, f);
  u += 0x7fffu + ((u >> 16) & 1u);
  return (unsigned short)(u >> 16);
}
__device__ __forceinline__ float bf2f(unsigned short s) {
  return __builtin_bit_cast(float, ((unsigned int)s) << 16);
}

__global__ __launch_bounds__(NTHREADS) void gs_kernel(const float* __restrict__ xg_all,
                                                      float* __restrict__ qg_all) {
  // Wave-column ownership: wave w owns cols [64w, 64w+64) of Xc and Qb for ALL
  // accesses (stage, commit, MFMA frags, update) -> those phases need no barriers;
  // only the cross-wave partial reduce does (2 barriers/chunk instead of 4).
  __shared__ __align__(16) float Xc[PANEL][XP];              // ~64 KB fp32 master panel
  __shared__ __align__(16) unsigned short Qb[2][PANEL][QP];  // ~66 KB double-buffered bf16 Q chunk
  __shared__ __align__(16) float Scr[4096];                  // 16 KB MFMA partials / csum partials
  __shared__ float Sm[PANEL][PANEL];
  __shared__ float Gm[PANEL][PANEL];
  __shared__ float LT[PANEL][PANEL];                         // LT[r][m] = L[m][r]
  __shared__ float rinv[NROW];

  const int t = threadIdx.x;
  const int lane = t & 63;
  const int w = t >> 6;
  const int wb = w << 6;                    // wave column base
  const int grow = lane >> 2;               // staging: row 0..15
  const int gcol = wb + ((lane & 3) << 2);  // staging: col base (+ rr*16), 4-lane 64B clusters
  const size_t off = (size_t)blockIdx.x * (NROW * D);
  const float* xg = xg_all + off;
  float* qg = qg_all + off;

  float csum = 0.0f;   // column t sum of squares
  float4 xr[4], qr[4]; // register prefetch buffers (X panel / Q chunk)

#define LDX(kk) do { const float* s_ = xg + (kk) * (PANEL * D); _Pragma("unroll") \
    for (int rr = 0; rr < 4; ++rr) xr[rr] = *(const float4*)(s_ + grow * D + gcol + rr * 16); } while (0)
#define LDQ(cc) do { const float* s_ = qg + (cc) * (PANEL * D); _Pragma("unroll") \
    for (int rr = 0; rr < 4; ++rr) qr[rr] = *(const float4*)(s_ + grow * D + gcol + rr * 16); } while (0)
#define COMMITX() do { _Pragma("unroll") \
    for (int rr = 0; rr < 4; ++rr) *(float4*)&Xc[grow][gcol + rr * 16] = xr[rr]; } while (0)
#define COMMITQ(buf) do { _Pragma("unroll") \
    for (int rr = 0; rr < 4; ++rr) { ushort4 u_; \
      u_.x = f2bf(qr[rr].x); u_.y = f2bf(qr[rr].y); u_.z = f2bf(qr[rr].z); u_.w = f2bf(qr[rr].w); \
      *(ushort4*)&Qb[buf][grow][gcol + rr * 16] = u_; } } while (0)

  // dots via MFMA: wave w covers K in [64w, 64w+64); partials to Scr[w*256..]
#define DOTS(buf) do { \
    const int m_ = lane & 15; \
    const int kb_ = lane >> 4; \
    floatx4 acc_ = {0.f, 0.f, 0.f, 0.f}; \
    _Pragma("unroll") \
    for (int h = 0; h < 2; ++h) { \
      const int kk = wb + kb_ * 8 + h * 32; \
      short8 a_ = *(const short8*)&Qb[buf][m_][kk]; \
      const float4 xlo = *(const float4*)&Xc[m_][kk]; \
      const float4 xhi = *(const float4*)&Xc[m_][kk + 4]; \
      short8 b_; \
      b_[0] = (short)f2bf(xlo.x); b_[1] = (short)f2bf(xlo.y); \
      b_[2] = (short)f2bf(xlo.z); b_[3] = (short)f2bf(xlo.w); \
      b_[4] = (short)f2bf(xhi.x); b_[5] = (short)f2bf(xhi.y); \
      b_[6] = (short)f2bf(xhi.z); b_[7] = (short)f2bf(xhi.w); \
      acc_ = __builtin_amdgcn_mfma_f32_16x16x32_bf16(a_, b_, acc_, 0, 0, 0); \
    } \
    _Pragma("unroll") \
    for (int r = 0; r < 4; ++r) Scr[w * 256 + r * 64 + lane] = acc_[r]; \
  } while (0)

#define GRAM() do { \
    const int m_ = lane & 15; \
    const int kb_ = lane >> 4; \
    floatx4 acc_ = {0.f, 0.f, 0.f, 0.f}; \
    _Pragma("unroll") \
    for (int h = 0; h < 2; ++h) { \
      const int kk = wb + kb_ * 8 + h * 32; \
      const float4 xlo = *(const float4*)&Xc[m_][kk]; \
      const float4 xhi = *(const float4*)&Xc[m_][kk + 4]; \
      short8 a_; \
      a_[0] = (short)f2bf(xlo.x); a_[1] = (short)f2bf(xlo.y); \
      a_[2] = (short)f2bf(xlo.z); a_[3] = (short)f2bf(xlo.w); \
      a_[4] = (short)f2bf(xhi.x); a_[5] = (short)f2bf(xhi.y); \
      a_[6] = (short)f2bf(xhi.z); a_[7] = (short)f2bf(xhi.w); \
      acc_ = __builtin_amdgcn_mfma_f32_16x16x32_bf16(a_, a_, acc_, 0, 0, 0); \
    } \
    _Pragma("unroll") \
    for (int r = 0; r < 4; ++r) Scr[w * 256 + r * 64 + lane] = acc_[r]; \
  } while (0)

  // all-thread reduce of 16 partial tiles; C/D map: col=lane&15, row=(lane>>4)*4+reg
#define REDUCE_TO(dst, scale_expr) do { \
    const int o_ = t >> 2, q_ = t & 3; \
    float s_ = Scr[q_ * 256 + o_] + Scr[(q_ + 4) * 256 + o_] + \
               Scr[(q_ + 8) * 256 + o_] + Scr[(q_ + 12) * 256 + o_]; \
    s_ += __shfl_xor(s_, 1); \
    s_ += __shfl_xor(s_, 2); \
    if (q_ == 0) { \
      const int p_ = o_ & 15; \
      const int j_ = ((o_ >> 4) & 3) * 4 + (o_ >> 6); \
      dst[j_][p_] = s_ * (scale_expr); \
    } \
  } while (0)

  // update: Xc[p][d] -= sum_j Sm[j][p] * Qb[j][d], wave-column-local (d in [wb, wb+64))
#define UPDATE(buf) do { \
    const int p0_ = (lane >> 4) << 2; \
    const int d0_ = wb + ((lane & 15) << 2); \
    float4 x0 = *(const float4*)&Xc[p0_ + 0][d0_]; \
    float4 x1 = *(const float4*)&Xc[p0_ + 1][d0_]; \
    float4 x2 = *(const float4*)&Xc[p0_ + 2][d0_]; \
    float4 x3 = *(const float4*)&Xc[p0_ + 3][d0_]; \
    _Pragma("unroll") \
    for (int j = 0; j < PANEL; ++j) { \
      const ushort4 qu = *(const ushort4*)&Qb[buf][j][d0_]; \
      const float4 sv = *(const float4*)&Sm[j][p0_]; \
      const float q0 = bf2f(qu.x), q1 = bf2f(qu.y), q2 = bf2f(qu.z), q3 = bf2f(qu.w); \
      x0.x -= sv.x * q0; x0.y -= sv.x * q1; x0.z -= sv.x * q2; x0.w -= sv.x * q3; \
      x1.x -= sv.y * q0; x1.y -= sv.y * q1; x1.z -= sv.y * q2; x1.w -= sv.y * q3; \
      x2.x -= sv.z * q0; x2.y -= sv.z * q1; x2.z -= sv.z * q2; x2.w -= sv.z * q3; \
      x3.x -= sv.w * q0; x3.y -= sv.w * q1; x3.z -= sv.w * q2; x3.w -= sv.w * q3; \
    } \
    *(float4*)&Xc[p0_ + 0][d0_] = x0; \
    *(float4*)&Xc[p0_ + 1][d0_] = x1; \
    *(float4*)&Xc[p0_ + 2][d0_] = x2; \
    *(float4*)&Xc[p0_ + 3][d0_] = x3; \
  } while (0)

  // prologue: stage panel 0 (wave-local, same-wave ds order makes it visible), prefetch panel 1
  LDX(0);
  COMMITX();
  if (NPANELS > 1) LDX(1);

  for (int k = 0; k < NPANELS; ++k) {
    const int i0 = k * PANEL;

    // ---- cross-panel corrections: 2 barriers per chunk, fused fat regions ----
    for (int c = 0; c < k; ++c) {
      if (c > 0) UPDATE((c - 1) & 1);          // finish chunk c-1 (wave-local cols)
      COMMITQ(c & 1);                          // stage chunk c (wave-local, same wave as readers)
      DOTS(c & 1);                             // MFMA partials -> Scr
      if (c + 1 < k) LDQ(c + 1);               // prefetch next consume
      else if (k + 1 < NPANELS) LDQ(0);        // ... = next panel's chunk 0
      __syncthreads();
      REDUCE_TO(Sm, rinv[c * PANEL + j_]);     // cross-wave reduce + rinv scale
      __syncthreads();
    }
    if (k > 0) UPDATE((k - 1) & 1);            // last chunk's update flows into Gram

    // ---- within-panel Gram via MFMA ----
    GRAM();
    __syncthreads();
    REDUCE_TO(Gm, 1.0f);
    __syncthreads();

    // ---- single-wave triangular solve in Gram domain (verbatim, verified) ----
    if (t < 64) {
      const int r = t & 15;
      float Lreg[PANEL];
      float rn[PANEL];
#pragma unroll
      for (int m = 0; m < PANEL; ++m) {
        const float g = Gm[r][m];
        float accL = (r == m) ? 1.0f : 0.0f;
        float nm = Gm[m][m];
#pragma unroll
        for (int j = 0; j < m; ++j) {
          float p = Lreg[j] * g;
          p += __shfl_xor(p, 1);
          p += __shfl_xor(p, 2);
          p += __shfl_xor(p, 4);
          p += __shfl_xor(p, 8);
          const float cj = p * rn[j];
          accL -= cj * Lreg[j];
          nm -= cj * p;
        }
        Lreg[m] = accL;
        rn[m] = 1.0f / nm;
        if (t == 0) rinv[i0 + m] = rn[m];
      }
      if (t < 16) {
#pragma unroll
        for (int m = 0; m < PANEL; ++m) LT[r][m] = Lreg[m];
      }
    }
    __syncthreads();

    // ---- gemm3: Q_panel = L * X_panel (fp32, exact diagonal) -> global + csum partials ----
    {
      const int m0 = (t >> 8) << 2;
      const int dg = (t & 255) << 2;
      float4 a0 = {0.f,0.f,0.f,0.f}, a1 = {0.f,0.f,0.f,0.f};
      float4 a2 = {0.f,0.f,0.f,0.f}, a3 = {0.f,0.f,0.f,0.f};
#pragma unroll
      for (int r = 0; r < PANEL; ++r) {
        const float4 xv = *(const float4*)&Xc[r][dg];
        const float4 lt = *(const float4*)&LT[r][m0];     // wave-uniform broadcast
        a0.x += lt.x * xv.x; a0.y += lt.x * xv.y; a0.z += lt.x * xv.z; a0.w += lt.x * xv.w;
        a1.x += lt.y * xv.x; a1.y += lt.y * xv.y; a1.z += lt.y * xv.z; a1.w += lt.y * xv.w;
        a2.x += lt.z * xv.x; a2.y += lt.z * xv.y; a2.z += lt.z * xv.z; a2.w += lt.z * xv.w;
        a3.x += lt.w * xv.x; a3.y += lt.w * xv.y; a3.z += lt.w * xv.z; a3.w += lt.w * xv.w;
      }
      *(float4*)(qg + (size_t)(i0 + m0 + 0) * D + dg) = a0;
      *(float4*)(qg + (size_t)(i0 + m0 + 1) * D + dg) = a1;
      *(float4*)(qg + (size_t)(i0 + m0 + 2) * D + dg) = a2;
      *(float4*)(qg + (size_t)(i0 + m0 + 3) * D + dg) = a3;
      float4 ps;
      ps.x = a0.x*a0.x + a1.x*a1.x + a2.x*a2.x + a3.x*a3.x;
      ps.y = a0.y*a0.y + a1.y*a1.y + a2.y*a2.y + a3.y*a3.y;
      ps.z = a0.z*a0.z + a1.z*a1.z + a2.z*a2.z + a3.z*a3.z;
      ps.w = a0.w*a0.w + a1.w*a1.w + a2.w*a2.w + a3.w*a3.w;
      *(float4*)&Scr[(t >> 8) * 1024 + dg] = ps;
    }
    __syncthreads();  // also drains gemm3's global stores (vmcnt(0) before s_barrier)

    // ---- csum + next-panel staging (Xc dead after gemm3; wave-local commits) ----
    csum += Scr[t] + Scr[1024 + t] + Scr[2048 + t] + Scr[3072 + t];
    if (k + 1 < NPANELS) {
      COMMITX();                               // stage X panel k+1
      if (k + 2 < NPANELS) LDX(k + 2);
    }
    if (k == 0 && NPANELS > 1) LDQ(0);         // panel-0 Q now visible
    __syncthreads();
  }

  // ---- final column-wise normalization, float4-vectorized ----
  Scr[t] = 1.0f / sqrtf(csum);
  __syncthreads();
  {
    float4* qv = (float4*)qg;
#pragma unroll 4
    for (int i = 0; i < 32; ++i) {
      const int f = i * 1024 + t;
      const float4 inv4 = *(const float4*)&Scr[(f & 255) << 2];
      float4 v = qv[f];
      v.x *= inv4.x; v.y *= inv4.y; v.z *= inv4.z; v.w *= inv4.w;
      qv[f] = v;
    }
  }
}

extern "C" void kernel_launch(void* const* d_in, const int* in_sizes, int n_in,
                              void* d_out, int out_size, void* d_ws, size_t ws_size,
                              hipStream_t stream) {
  const float* x = (const float*)d_in[0];
  float* out = (float*)d_out;
  gs_kernel<<<dim3(256), dim3(NTHREADS), 0, stream>>>(x, out);
}